// Round 2
// baseline (227.265 us; speedup 1.0000x reference)
//
#include <hip/hip_runtime.h>
#include <hip/hip_bf16.h>

#define BN 16
#define TN 2048
#define DN 64
#define EN 512

using f32x4  = __attribute__((ext_vector_type(4))) float;
using bf16x8 = __attribute__((ext_vector_type(8))) short;

static __device__ __forceinline__ short f2bf(float f) {
    __hip_bfloat16 h = __float2bfloat16(f);
    return __builtin_bit_cast(short, h);
}

// ---------------------------------------------------------------------------
// Kernel A: Q = x @ Wq + bq  (f32 accumulate), emit Q as bf16 row-major and
// bf16 transposed (QT[b][d][t]) for the PV pass. (unchanged from R1)
// ---------------------------------------------------------------------------
__global__ __launch_bounds__(512, 4) void qproj_kernel(
    const float* __restrict__ x, const float* __restrict__ Wq,
    const float* __restrict__ bq, short* __restrict__ Qb,
    short* __restrict__ QTb)
{
    __shared__ float xlds[8][EN];      // 16 KB: 8 staged rows of x
    __shared__ float red[8][8][64];    // 16 KB: [row][wave(k-slice)][col]
    __shared__ short tl[64][68];       // 8.7 KB: [d][local row] bf16 (padded)

    const int tid = threadIdx.x;
    const int w = tid >> 6;            // wave id = k-slice
    const int c = tid & 63;            // output column d
    const int rowbase = blockIdx.x * 64;
    const int b = rowbase >> 11;
    const int tbase = rowbase & (TN - 1);

    float wreg[64];
    #pragma unroll
    for (int i = 0; i < 64; ++i)
        wreg[i] = Wq[(w * 64 + i) * 64 + c];
    const float bias = bq[c];

    for (int ch = 0; ch < 8; ++ch) {
        const float4* xsrc =
            reinterpret_cast<const float4*>(x + (size_t)(rowbase + ch * 8) * EN);
        float4* xdst = reinterpret_cast<float4*>(&xlds[0][0]);
        xdst[tid] = xsrc[tid];
        xdst[tid + 512] = xsrc[tid + 512];
        __syncthreads();

        float acc[8];
        #pragma unroll
        for (int rr = 0; rr < 8; ++rr) {
            const float4* xp =
                reinterpret_cast<const float4*>(&xlds[rr][w * 64]);
            float a = 0.f;
            #pragma unroll
            for (int i = 0; i < 16; ++i) {
                float4 xv = xp[i];
                a += xv.x * wreg[i * 4 + 0];
                a += xv.y * wreg[i * 4 + 1];
                a += xv.z * wreg[i * 4 + 2];
                a += xv.w * wreg[i * 4 + 3];
            }
            acc[rr] = a;
        }
        #pragma unroll
        for (int rr = 0; rr < 8; ++rr) red[rr][w][c] = acc[rr];
        __syncthreads();

        float q = bias;
        #pragma unroll
        for (int k = 0; k < 8; ++k) q += red[w][k][c];

        const int row = rowbase + ch * 8 + w;
        short qb = f2bf(q);
        Qb[(size_t)row * DN + c] = qb;
        tl[c][ch * 8 + w] = qb;
    }
    __syncthreads();

    #pragma unroll
    for (int it = 0; it < 2; ++it) {
        int idx = it * 512 + tid;
        int d = idx >> 4;
        int j4 = (idx & 15) * 4;
        short4 v = *reinterpret_cast<const short4*>(&tl[d][j4]);
        *reinterpret_cast<short4*>(
            &QTb[((size_t)(b * 64 + d)) * TN + tbase + j4]) = v;
    }
}

// ---------------------------------------------------------------------------
// Kernel B: column-softmax denominators via row sums (S symmetric).
// RESTRUCTURED: one 16-row j-tile per block; the 4 waves split the i-range
// 4-way (32 iters each); cross-wave reduce through LDS. Grid 128x16.
// ---------------------------------------------------------------------------
__global__ __launch_bounds__(256, 8) void stats_kernel(
    const short* __restrict__ Qb, float* __restrict__ linv)
{
    __shared__ float ldsL[4][16];
    const int tid = threadIdx.x;
    const int lane = tid & 63;
    const int wv = tid >> 6;
    const int c = lane & 15;
    const int g = lane >> 4;
    const int b = blockIdx.y;
    const int jbase = blockIdx.x * 16;
    const short* Qbb = Qb + (size_t)b * TN * DN;

    // A frag: rows jbase..jbase+15 (same for all 4 waves)
    bf16x8 a0 = *reinterpret_cast<const bf16x8*>(Qbb + (size_t)(jbase + c) * DN + g * 8);
    bf16x8 a1 = *reinterpret_cast<const bf16x8*>(Qbb + (size_t)(jbase + c) * DN + g * 8 + 32);

    float l[4] = {0.f, 0.f, 0.f, 0.f};
    const int ilo = wv * (TN / 4);
    for (int ii = 0; ii < TN / 4; ii += 16) {
        const int ib = ilo + ii;
        bf16x8 b0 = *reinterpret_cast<const bf16x8*>(Qbb + (size_t)(ib + c) * DN + g * 8);
        bf16x8 b1 = *reinterpret_cast<const bf16x8*>(Qbb + (size_t)(ib + c) * DN + g * 8 + 32);
        f32x4 acc = {0.f, 0.f, 0.f, 0.f};
        acc = __builtin_amdgcn_mfma_f32_16x16x32_bf16(a0, b0, acc, 0, 0, 0);
        acc = __builtin_amdgcn_mfma_f32_16x16x32_bf16(a1, b1, acc, 0, 0, 0);
        #pragma unroll
        for (int r = 0; r < 4; ++r)
            l[r] += __expf(acc[r] * 0.125f);
    }
    // reduce across the 16 column-lanes (i-direction within wave)
    #pragma unroll
    for (int r = 0; r < 4; ++r) {
        float v = l[r];
        v += __shfl_xor(v, 1);
        v += __shfl_xor(v, 2);
        v += __shfl_xor(v, 4);
        v += __shfl_xor(v, 8);
        l[r] = v;
    }
    if (c == 0) {
        #pragma unroll
        for (int r = 0; r < 4; ++r) ldsL[wv][g * 4 + r] = l[r];
    }
    __syncthreads();
    if (tid < 16) {
        float s = ldsL[0][tid] + ldsL[1][tid] + ldsL[2][tid] + ldsL[3][tid];
        linv[(size_t)b * TN + jbase + tid] = 1.0f / s;
    }
}

// ---------------------------------------------------------------------------
// Kernel C: out[i,:] = sum_j exp(s[i,j]) * (1/l_j) * Q[j,:]
// RESTRUCTURED: one 16-row i-tile per block; the 4 waves split the j-range
// 4-way (16 iters of 32 j each); partial outT accumulators reduced through
// LDS, transposed + coalesced f32 stores in the same epilogue. Grid 128x16.
// ---------------------------------------------------------------------------
__global__ __launch_bounds__(256, 4) void pv_kernel(
    const short* __restrict__ Qb, const short* __restrict__ QTb,
    const float* __restrict__ linv, float* __restrict__ out)
{
    __shared__ float red[4][64][17];   // 17.4 KB, pad 17 (coprime 32)
    const int tid = threadIdx.x;
    const int lane = tid & 63;
    const int wv = tid >> 6;
    const int c = lane & 15;
    const int g = lane >> 4;
    const int b = blockIdx.y;
    const int iblock = blockIdx.x * 16;
    const short* Qbb = Qb + (size_t)b * TN * DN;
    const short* QTbb = QTb + (size_t)b * DN * TN;
    const float* linvb = linv + (size_t)b * TN;

    // invariant B frags: B[k=d][n=i] = Q[iblock+n][k] (same for all waves)
    bf16x8 bi0 = *reinterpret_cast<const bf16x8*>(Qbb + (size_t)(iblock + c) * DN + g * 8);
    bf16x8 bi1 = *reinterpret_cast<const bf16x8*>(Qbb + (size_t)(iblock + c) * DN + g * 8 + 32);

    f32x4 o[4] = {{0.f,0.f,0.f,0.f},{0.f,0.f,0.f,0.f},{0.f,0.f,0.f,0.f},{0.f,0.f,0.f,0.f}};

    const int jlo = wv * (TN / 4);
    for (int jj = 0; jj < TN / 4; jj += 32) {
        const int jb = jlo + jj;
        float p0[4], p1[4];
        {
            bf16x8 a0 = *reinterpret_cast<const bf16x8*>(Qbb + (size_t)(jb + c) * DN + g * 8);
            bf16x8 a1 = *reinterpret_cast<const bf16x8*>(Qbb + (size_t)(jb + c) * DN + g * 8 + 32);
            f32x4 acc = {0.f, 0.f, 0.f, 0.f};
            acc = __builtin_amdgcn_mfma_f32_16x16x32_bf16(a0, bi0, acc, 0, 0, 0);
            acc = __builtin_amdgcn_mfma_f32_16x16x32_bf16(a1, bi1, acc, 0, 0, 0);
            #pragma unroll
            for (int r = 0; r < 4; ++r)
                p0[r] = __expf(acc[r] * 0.125f) * linvb[jb + g * 4 + r];
        }
        {
            bf16x8 a0 = *reinterpret_cast<const bf16x8*>(Qbb + (size_t)(jb + 16 + c) * DN + g * 8);
            bf16x8 a1 = *reinterpret_cast<const bf16x8*>(Qbb + (size_t)(jb + 16 + c) * DN + g * 8 + 32);
            f32x4 acc = {0.f, 0.f, 0.f, 0.f};
            acc = __builtin_amdgcn_mfma_f32_16x16x32_bf16(a0, bi0, acc, 0, 0, 0);
            acc = __builtin_amdgcn_mfma_f32_16x16x32_bf16(a1, bi1, acc, 0, 0, 0);
            #pragma unroll
            for (int r = 0; r < 4; ++r)
                p1[r] = __expf(acc[r] * 0.125f) * linvb[jb + 16 + g * 4 + r];
        }

        // transpose P^T (D-layout) -> PV B-fragment (lane-uniform src regs)
        short bt[8];
        #pragma unroll
        for (int t = 0; t < 8; ++t) {
            int src = (2 * (g & 1) + (t >> 2)) * 16 + c;
            float va = __shfl(p0[t & 3], src);
            float vb = __shfl(p1[t & 3], src);
            bt[t] = f2bf((g < 2) ? va : vb);
        }
        bf16x8 bp;
        #pragma unroll
        for (int t = 0; t < 8; ++t) bp[t] = bt[t];

        // outT[d][i] += QT[d][j-slice] * P^T[j-slice][i]
        #pragma unroll
        for (int dt = 0; dt < 4; ++dt) {
            bf16x8 aq = *reinterpret_cast<const bf16x8*>(
                QTbb + (size_t)(dt * 16 + c) * TN + jb + g * 8);
            o[dt] = __builtin_amdgcn_mfma_f32_16x16x32_bf16(aq, bp, o[dt], 0, 0, 0);
        }
    }

    // cross-wave reduce + transpose + coalesced stores
    #pragma unroll
    for (int dt = 0; dt < 4; ++dt) {
        #pragma unroll
        for (int r = 0; r < 4; ++r)
            red[wv][dt * 16 + g * 4 + r][c] = o[dt][r];
    }
    __syncthreads();
    float* outb = out + (size_t)b * TN * DN + (size_t)iblock * DN;
    #pragma unroll
    for (int it = 0; it < 4; ++it) {
        int idx = it * 256 + tid;       // 0..1023 = 16 rows x 64 cols
        int il = idx >> 6;
        int d = idx & 63;
        outb[idx] = red[0][d][il] + red[1][d][il] + red[2][d][il] + red[3][d][il];
    }
}

extern "C" void kernel_launch(void* const* d_in, const int* in_sizes, int n_in,
                              void* d_out, int out_size, void* d_ws, size_t ws_size,
                              hipStream_t stream) {
    const float* x  = (const float*)d_in[0];
    const float* Wq = (const float*)d_in[1];
    const float* bq = (const float*)d_in[2];
    float* out = (float*)d_out;

    short* Qb  = (short*)d_ws;                          // 4 MB
    short* QTb = Qb + (size_t)BN * TN * DN;             // 4 MB
    float* linv = (float*)(QTb + (size_t)BN * TN * DN); // 128 KB

    qproj_kernel<<<dim3(512), dim3(512), 0, stream>>>(x, Wq, bq, Qb, QTb);
    stats_kernel<<<dim3(TN / 16, BN), dim3(256), 0, stream>>>(Qb, linv);
    pv_kernel<<<dim3(TN / 16, BN), dim3(256), 0, stream>>>(Qb, QTb, linv, out);
}

// Round 5
// 114.852 us; speedup vs baseline: 1.9788x; 1.9788x over previous
//
#include <hip/hip_runtime.h>
#include <hip/hip_bf16.h>

#define BN 16
#define TN 2048
#define DN 64
#define EN 512
#define PAD 72   // bf16 row stride: 144B rows, 16B-aligned, conflict-free

using f32x4  = __attribute__((ext_vector_type(4))) float;
using bf16x8 = __attribute__((ext_vector_type(8))) short;
using bf16x4 = __attribute__((ext_vector_type(4))) short;

static __device__ __forceinline__ short f2bf(float f) {
    __hip_bfloat16 h = __float2bfloat16(f);
    return __builtin_bit_cast(short, h);
}

// ---------------------------------------------------------------------------
// Kernel A: Q = x @ Wq + bq  (f32 accumulate), emit Q bf16 row-major + QT
// (transposed). Unchanged.
// ---------------------------------------------------------------------------
__global__ __launch_bounds__(512, 4) void qproj_kernel(
    const float* __restrict__ x, const float* __restrict__ Wq,
    const float* __restrict__ bq, short* __restrict__ Qb,
    short* __restrict__ QTb)
{
    __shared__ float xlds[8][EN];
    __shared__ float red[8][8][64];
    __shared__ short tl[64][68];

    const int tid = threadIdx.x;
    const int w = tid >> 6;
    const int c = tid & 63;
    const int rowbase = blockIdx.x * 64;
    const int b = rowbase >> 11;
    const int tbase = rowbase & (TN - 1);

    float wreg[64];
    #pragma unroll
    for (int i = 0; i < 64; ++i)
        wreg[i] = Wq[(w * 64 + i) * 64 + c];
    const float bias = bq[c];

    for (int ch = 0; ch < 8; ++ch) {
        const float4* xsrc =
            reinterpret_cast<const float4*>(x + (size_t)(rowbase + ch * 8) * EN);
        float4* xdst = reinterpret_cast<float4*>(&xlds[0][0]);
        xdst[tid] = xsrc[tid];
        xdst[tid + 512] = xsrc[tid + 512];
        __syncthreads();

        float acc[8];
        #pragma unroll
        for (int rr = 0; rr < 8; ++rr) {
            const float4* xp =
                reinterpret_cast<const float4*>(&xlds[rr][w * 64]);
            float a = 0.f;
            #pragma unroll
            for (int i = 0; i < 16; ++i) {
                float4 xv = xp[i];
                a += xv.x * wreg[i * 4 + 0];
                a += xv.y * wreg[i * 4 + 1];
                a += xv.z * wreg[i * 4 + 2];
                a += xv.w * wreg[i * 4 + 3];
            }
            acc[rr] = a;
        }
        #pragma unroll
        for (int rr = 0; rr < 8; ++rr) red[rr][w][c] = acc[rr];
        __syncthreads();

        float q = bias;
        #pragma unroll
        for (int k = 0; k < 8; ++k) q += red[w][k][c];

        const int row = rowbase + ch * 8 + w;
        short qb = f2bf(q);
        Qb[(size_t)row * DN + c] = qb;
        tl[c][ch * 8 + w] = qb;
    }
    __syncthreads();

    #pragma unroll
    for (int it = 0; it < 2; ++it) {
        int idx = it * 512 + tid;
        int d = idx >> 4;
        int j4 = (idx & 15) * 4;
        short4 v = *reinterpret_cast<const short4*>(&tl[d][j4]);
        *reinterpret_cast<short4*>(
            &QTb[((size_t)(b * 64 + d)) * TN + tbase + j4]) = v;
    }
}

// ---------------------------------------------------------------------------
// Kernel B: column-softmax denominators (= row sums of exp(S/8), S symmetric).
// Block owns 64 j-rows (wave wv -> 16 rows, A-frags in regs). i-loop stages
// Q[64][64] tiles in padded LDS. R5 FIX: each staging thread covers 16 shorts
// (32 B) via TWO bf16x8 load/store pairs — R3/R4 only staged half the tile.
// ---------------------------------------------------------------------------
__global__ __launch_bounds__(256, 4) void stats_kernel(
    const short* __restrict__ Qb, float* __restrict__ linv)
{
    __shared__ short Qt[64 * PAD];
    const int tid = threadIdx.x;
    const int lane = tid & 63;
    const int wv = tid >> 6;
    const int c = lane & 15;
    const int g = lane >> 4;
    const int b = blockIdx.y;
    const int jbase = blockIdx.x * 64 + wv * 16;
    const short* Qbb = Qb + (size_t)b * TN * DN;

    bf16x8 a0 = *reinterpret_cast<const bf16x8*>(Qbb + (size_t)(jbase + c) * DN + g * 8);
    bf16x8 a1 = *reinterpret_cast<const bf16x8*>(Qbb + (size_t)(jbase + c) * DN + g * 8 + 32);

    const int srow = tid >> 2;      // 0..63 staged row
    const int schk = tid & 3;       // 0..3, each = 16 shorts (32 B)

    float l[4] = {0.f, 0.f, 0.f, 0.f};
    for (int ib = 0; ib < TN; ib += 64) {
        bf16x8 v0 = *reinterpret_cast<const bf16x8*>(
            Qbb + (size_t)(ib + srow) * DN + schk * 16);
        bf16x8 v1 = *reinterpret_cast<const bf16x8*>(
            Qbb + (size_t)(ib + srow) * DN + schk * 16 + 8);
        __syncthreads();   // previous step's reads done before overwrite
        *reinterpret_cast<bf16x8*>(&Qt[srow * PAD + schk * 16]) = v0;
        *reinterpret_cast<bf16x8*>(&Qt[srow * PAD + schk * 16 + 8]) = v1;
        __syncthreads();

        #pragma unroll
        for (int it = 0; it < 4; ++it) {
            bf16x8 b0 = *reinterpret_cast<const bf16x8*>(&Qt[(it * 16 + c) * PAD + g * 8]);
            bf16x8 b1 = *reinterpret_cast<const bf16x8*>(&Qt[(it * 16 + c) * PAD + g * 8 + 32]);
            f32x4 acc = {0.f, 0.f, 0.f, 0.f};
            acc = __builtin_amdgcn_mfma_f32_16x16x32_bf16(a0, b0, acc, 0, 0, 0);
            acc = __builtin_amdgcn_mfma_f32_16x16x32_bf16(a1, b1, acc, 0, 0, 0);
            #pragma unroll
            for (int r = 0; r < 4; ++r)
                l[r] += __expf(acc[r] * 0.125f);
        }
    }
    #pragma unroll
    for (int r = 0; r < 4; ++r) {
        float v = l[r];
        v += __shfl_xor(v, 1);
        v += __shfl_xor(v, 2);
        v += __shfl_xor(v, 4);
        v += __shfl_xor(v, 8);
        l[r] = v;
    }
    if (c == 0) {
        #pragma unroll
        for (int r = 0; r < 4; ++r)
            linv[(size_t)b * TN + jbase + g * 4 + r] = 1.0f / l[r];
    }
}

// ---------------------------------------------------------------------------
// Kernel C: out[i,:] = sum_j exp(S[i,j]/8) * linv[j] * Q[j,:]
// Block = 128 i (4 waves x 32 i). Per 64-j step:
//   stage Q/QT/linv tiles (R5 FIX: full 32 B per thread) -> barrier
//   phase A: MFMA1 (S^T) -> exp*linv -> ds_write Pt (D-layout, b64)
//   barrier
//   phase B: MFMA2 reads Pt as exact B-frags (b128) + QTt rows, accumulates.
// Direct-scatter f32x4 epilogue.
// ---------------------------------------------------------------------------
__global__ __launch_bounds__(256, 4) void pv_kernel(
    const short* __restrict__ Qb, const short* __restrict__ QTb,
    const float* __restrict__ linv, float* __restrict__ out)
{
    __shared__ short Qt[64 * PAD];        // Q[j-local][d]
    __shared__ short QTt[64 * PAD];       // QT[d][j-local]
    __shared__ short Pt[8][16 * PAD];     // per (wave,ihalf): P[i-local][j-local]
    __shared__ float lv[64];

    const int tid = threadIdx.x;
    const int lane = tid & 63;
    const int wv = tid >> 6;
    const int c = lane & 15;
    const int g = lane >> 4;
    const int b = blockIdx.y;
    const int iblock = blockIdx.x * 128;
    const int ibase = iblock + wv * 32;
    const short* Qbb = Qb + (size_t)b * TN * DN;
    const short* QTbb = QTb + (size_t)b * DN * TN;
    const float* linvb = linv + (size_t)b * TN;

    bf16x8 bi[2][2];
    #pragma unroll
    for (int ih = 0; ih < 2; ++ih) {
        bi[ih][0] = *reinterpret_cast<const bf16x8*>(
            Qbb + (size_t)(ibase + ih * 16 + c) * DN + g * 8);
        bi[ih][1] = *reinterpret_cast<const bf16x8*>(
            Qbb + (size_t)(ibase + ih * 16 + c) * DN + g * 8 + 32);
    }

    f32x4 o[4][2];
    #pragma unroll
    for (int dt = 0; dt < 4; ++dt)
        #pragma unroll
        for (int ih = 0; ih < 2; ++ih)
            o[dt][ih] = (f32x4){0.f, 0.f, 0.f, 0.f};

    const int srow = tid >> 2;
    const int schk = tid & 3;

    for (int jb = 0; jb < TN; jb += 64) {
        // issue staging loads early (coalesced 16B), write after barrier
        bf16x8 vq0 = *reinterpret_cast<const bf16x8*>(
            Qbb + (size_t)(jb + srow) * DN + schk * 16);
        bf16x8 vq1 = *reinterpret_cast<const bf16x8*>(
            Qbb + (size_t)(jb + srow) * DN + schk * 16 + 8);
        bf16x8 vt0 = *reinterpret_cast<const bf16x8*>(
            QTbb + (size_t)srow * TN + jb + schk * 16);
        bf16x8 vt1 = *reinterpret_cast<const bf16x8*>(
            QTbb + (size_t)srow * TN + jb + schk * 16 + 8);
        float vl = (tid < 64) ? linvb[jb + tid] : 0.f;
        __syncthreads();   // all reads of Qt/QTt/lv/Pt from prev iter done
        *reinterpret_cast<bf16x8*>(&Qt[srow * PAD + schk * 16]) = vq0;
        *reinterpret_cast<bf16x8*>(&Qt[srow * PAD + schk * 16 + 8]) = vq1;
        *reinterpret_cast<bf16x8*>(&QTt[srow * PAD + schk * 16]) = vt0;
        *reinterpret_cast<bf16x8*>(&QTt[srow * PAD + schk * 16 + 8]) = vt1;
        if (tid < 64) lv[tid] = vl;
        __syncthreads();

        // --- phase A: MFMA1 S^T tiles -> P -> Pt (D-layout b64 writes) ---
        #pragma unroll
        for (int jt = 0; jt < 4; ++jt) {
            bf16x8 a0 = *reinterpret_cast<const bf16x8*>(&Qt[(jt * 16 + c) * PAD + g * 8]);
            bf16x8 a1 = *reinterpret_cast<const bf16x8*>(&Qt[(jt * 16 + c) * PAD + g * 8 + 32]);
            f32x4 lw = *reinterpret_cast<const f32x4*>(&lv[jt * 16 + g * 4]);
            #pragma unroll
            for (int ih = 0; ih < 2; ++ih) {
                f32x4 acc = {0.f, 0.f, 0.f, 0.f};
                acc = __builtin_amdgcn_mfma_f32_16x16x32_bf16(a0, bi[ih][0], acc, 0, 0, 0);
                acc = __builtin_amdgcn_mfma_f32_16x16x32_bf16(a1, bi[ih][1], acc, 0, 0, 0);
                bf16x4 pw;
                #pragma unroll
                for (int r = 0; r < 4; ++r)
                    pw[r] = f2bf(__expf(acc[r] * 0.125f) * lw[r]);
                *reinterpret_cast<bf16x4*>(
                    &Pt[wv * 2 + ih][c * PAD + jt * 16 + g * 4]) = pw;
            }
        }
        __syncthreads();   // Pt writes visible before B-frag reads

        // --- phase B: MFMA2 outT[d][i] += QT[d][j] * P[j][i] ---
        #pragma unroll
        for (int dt = 0; dt < 4; ++dt) {
            bf16x8 aq0 = *reinterpret_cast<const bf16x8*>(&QTt[(dt * 16 + c) * PAD + g * 8]);
            bf16x8 aq1 = *reinterpret_cast<const bf16x8*>(&QTt[(dt * 16 + c) * PAD + 32 + g * 8]);
            #pragma unroll
            for (int ih = 0; ih < 2; ++ih) {
                bf16x8 p0 = *reinterpret_cast<const bf16x8*>(&Pt[wv * 2 + ih][c * PAD + g * 8]);
                bf16x8 p1 = *reinterpret_cast<const bf16x8*>(&Pt[wv * 2 + ih][c * PAD + 32 + g * 8]);
                o[dt][ih] = __builtin_amdgcn_mfma_f32_16x16x32_bf16(aq0, p0, o[dt][ih], 0, 0, 0);
                o[dt][ih] = __builtin_amdgcn_mfma_f32_16x16x32_bf16(aq1, p1, o[dt][ih], 0, 0, 0);
            }
        }
    }

    // epilogue: lane holds outT[dt*16+g*4+r][ibase+ih*16+c] -> float4 scatter
    float* outb = out + (size_t)b * TN * DN;
    #pragma unroll
    for (int dt = 0; dt < 4; ++dt) {
        #pragma unroll
        for (int ih = 0; ih < 2; ++ih) {
            float4 v4;
            v4.x = o[dt][ih][0]; v4.y = o[dt][ih][1];
            v4.z = o[dt][ih][2]; v4.w = o[dt][ih][3];
            *reinterpret_cast<float4*>(
                &outb[(size_t)(ibase + ih * 16 + c) * DN + dt * 16 + g * 4]) = v4;
        }
    }
}

extern "C" void kernel_launch(void* const* d_in, const int* in_sizes, int n_in,
                              void* d_out, int out_size, void* d_ws, size_t ws_size,
                              hipStream_t stream) {
    const float* x  = (const float*)d_in[0];
    const float* Wq = (const float*)d_in[1];
    const float* bq = (const float*)d_in[2];
    float* out = (float*)d_out;

    short* Qb  = (short*)d_ws;                          // 4 MB
    short* QTb = Qb + (size_t)BN * TN * DN;             // 4 MB
    float* linv = (float*)(QTb + (size_t)BN * TN * DN); // 128 KB

    qproj_kernel<<<dim3(512), dim3(512), 0, stream>>>(x, Wq, bq, Qb, QTb);
    stats_kernel<<<dim3(TN / 64, BN), dim3(256), 0, stream>>>(Qb, linv);
    pv_kernel<<<dim3(TN / 128, BN), dim3(256), 0, stream>>>(Qb, QTb, linv, out);
}

// Round 6
// 81.234 us; speedup vs baseline: 2.7977x; 1.4138x over previous
//
#include <hip/hip_runtime.h>
#include <hip/hip_bf16.h>

#define BN 16
#define TN 2048
#define DN 64
#define EN 512
#define PAD 72   // bf16 row stride: 144B rows, 16B-aligned, conflict-free enough

using f32x4  = __attribute__((ext_vector_type(4))) float;
using bf16x8 = __attribute__((ext_vector_type(8))) short;
using bf16x4 = __attribute__((ext_vector_type(4))) short;

static __device__ __forceinline__ short f2bf(float f) {
    __hip_bfloat16 h = __float2bfloat16(f);
    return __builtin_bit_cast(short, h);
}
static __device__ __forceinline__ float bf2f(short s) {
    return __bfloat162float(__builtin_bit_cast(__hip_bfloat16, s));
}

// ---------------------------------------------------------------------------
// Kernel W: split W^T into bf16 hi + lo (WTh[n][k], WTl[n][k]).
// hi+lo reconstruct W to ~1e-5 relative; done once, 128 KB of work.
// ---------------------------------------------------------------------------
__global__ __launch_bounds__(256) void wprep_kernel(
    const float* __restrict__ Wq, short* __restrict__ WTh,
    short* __restrict__ WTl)
{
    __shared__ float wlds[64][65];
    const int tid = threadIdx.x;
    const int k0 = blockIdx.x * 64;
    #pragma unroll
    for (int it = 0; it < 16; ++it) {
        int idx = it * 256 + tid;          // 0..4095
        int k = idx >> 6, n = idx & 63;
        wlds[k][n] = Wq[(size_t)(k0 + k) * 64 + n];
    }
    __syncthreads();
    #pragma unroll
    for (int it = 0; it < 16; ++it) {
        int idx = it * 256 + tid;
        int n = idx >> 6, k = idx & 63;
        float v = wlds[k][n];
        short h = f2bf(v);
        short l = f2bf(v - bf2f(h));
        WTh[(size_t)n * EN + k0 + k] = h;
        WTl[(size_t)n * EN + k0 + k] = l;
    }
}

// ---------------------------------------------------------------------------
// Kernel A (v2): Q = x @ W + bq via MFMA: bf16(x) * (Wh + Wl), f32 accum.
// Block = 256 thr (4 waves), 64 rows; K-loop 16 steps of 32 with register
// prefetch. Emits Qb row-major + QTb (LDS transpose).
// ---------------------------------------------------------------------------
__global__ __launch_bounds__(256, 2) void qproj_kernel(
    const float* __restrict__ x, const short* __restrict__ WTh,
    const short* __restrict__ WTl, const float* __restrict__ bq,
    short* __restrict__ Qb, short* __restrict__ QTb)
{
    __shared__ short xh[64 * 40];      // x tile bf16 [row][k0..k0+31], stride 40
    __shared__ short wth[64 * 40];     // W^T hi [n][k], stride 40
    __shared__ short wtl[64 * 40];     // W^T lo
    __shared__ short tl[64][68];       // transpose buffer for QTb

    const int tid = threadIdx.x;
    const int lane = tid & 63;
    const int wv = tid >> 6;
    const int c = lane & 15;
    const int g = lane >> 4;
    const int rowbase = blockIdx.x * 64;
    const int b = rowbase >> 11;
    const int tbase = rowbase & (TN - 1);

    const int sr = tid >> 3;           // 0..31 staged row/n
    const int sc4 = tid & 7;           // 4-elem chunk within 32-k

    // prefetch K-step 0
    float4 xa = *reinterpret_cast<const float4*>(&x[(size_t)(rowbase + sr) * EN + sc4 * 4]);
    float4 xb = *reinterpret_cast<const float4*>(&x[(size_t)(rowbase + 32 + sr) * EN + sc4 * 4]);
    bf16x4 wa = *reinterpret_cast<const bf16x4*>(&WTh[(size_t)sr * EN + sc4 * 4]);
    bf16x4 wb = *reinterpret_cast<const bf16x4*>(&WTh[(size_t)(32 + sr) * EN + sc4 * 4]);
    bf16x4 la = *reinterpret_cast<const bf16x4*>(&WTl[(size_t)sr * EN + sc4 * 4]);
    bf16x4 lb = *reinterpret_cast<const bf16x4*>(&WTl[(size_t)(32 + sr) * EN + sc4 * 4]);

    f32x4 acc[4];
    #pragma unroll
    for (int nt = 0; nt < 4; ++nt) acc[nt] = (f32x4){0.f, 0.f, 0.f, 0.f};

    for (int ks = 0; ks < EN; ks += 32) {
        __syncthreads();   // prev step's frag reads done
        bf16x4 h0, h1;
        #pragma unroll
        for (int j = 0; j < 4; ++j) { h0[j] = f2bf(xa[j]); h1[j] = f2bf(xb[j]); }
        *reinterpret_cast<bf16x4*>(&xh[sr * 40 + sc4 * 4]) = h0;
        *reinterpret_cast<bf16x4*>(&xh[(32 + sr) * 40 + sc4 * 4]) = h1;
        *reinterpret_cast<bf16x4*>(&wth[sr * 40 + sc4 * 4]) = wa;
        *reinterpret_cast<bf16x4*>(&wth[(32 + sr) * 40 + sc4 * 4]) = wb;
        *reinterpret_cast<bf16x4*>(&wtl[sr * 40 + sc4 * 4]) = la;
        *reinterpret_cast<bf16x4*>(&wtl[(32 + sr) * 40 + sc4 * 4]) = lb;

        // prefetch next K-step (clamped reload on last iter)
        const int kn = (ks + 32 < EN) ? ks + 32 : ks;
        xa = *reinterpret_cast<const float4*>(&x[(size_t)(rowbase + sr) * EN + kn + sc4 * 4]);
        xb = *reinterpret_cast<const float4*>(&x[(size_t)(rowbase + 32 + sr) * EN + kn + sc4 * 4]);
        wa = *reinterpret_cast<const bf16x4*>(&WTh[(size_t)sr * EN + kn + sc4 * 4]);
        wb = *reinterpret_cast<const bf16x4*>(&WTh[(size_t)(32 + sr) * EN + kn + sc4 * 4]);
        la = *reinterpret_cast<const bf16x4*>(&WTl[(size_t)sr * EN + kn + sc4 * 4]);
        lb = *reinterpret_cast<const bf16x4*>(&WTl[(size_t)(32 + sr) * EN + kn + sc4 * 4]);
        __syncthreads();

        bf16x8 av = *reinterpret_cast<const bf16x8*>(&xh[(wv * 16 + c) * 40 + g * 8]);
        #pragma unroll
        for (int nt = 0; nt < 4; ++nt) {
            bf16x8 bh = *reinterpret_cast<const bf16x8*>(&wth[(nt * 16 + c) * 40 + g * 8]);
            bf16x8 bl = *reinterpret_cast<const bf16x8*>(&wtl[(nt * 16 + c) * 40 + g * 8]);
            acc[nt] = __builtin_amdgcn_mfma_f32_16x16x32_bf16(av, bh, acc[nt], 0, 0, 0);
            acc[nt] = __builtin_amdgcn_mfma_f32_16x16x32_bf16(av, bl, acc[nt], 0, 0, 0);
        }
    }

    // epilogue: D[m=g*4+r][n=nt*16+c]; add bias, write Qb direct + tl for QTb
    __syncthreads();
    #pragma unroll
    for (int nt = 0; nt < 4; ++nt) {
        const float bias = bq[nt * 16 + c];
        #pragma unroll
        for (int r = 0; r < 4; ++r) {
            const int row = wv * 16 + g * 4 + r;
            short qb = f2bf(acc[nt][r] + bias);
            Qb[(size_t)(rowbase + row) * DN + nt * 16 + c] = qb;
            tl[nt * 16 + c][row] = qb;
        }
    }
    __syncthreads();
    #pragma unroll
    for (int it = 0; it < 4; ++it) {
        int idx = it * 256 + tid;          // 0..1023
        int d = idx >> 4;
        int j4 = (idx & 15) * 4;
        *reinterpret_cast<short4*>(&QTb[((size_t)(b * 64 + d)) * TN + tbase + j4]) =
            *reinterpret_cast<const short4*>(&tl[d][j4]);
    }
}

// ---------------------------------------------------------------------------
// Kernel B: column-softmax denominators (= row sums of exp(S/8), S symmetric).
// v4: register prefetch one i-tile ahead so barrier drains wait on old loads.
// ---------------------------------------------------------------------------
__global__ __launch_bounds__(256, 2) void stats_kernel(
    const short* __restrict__ Qb, float* __restrict__ linv)
{
    __shared__ short Qt[64 * PAD];
    const int tid = threadIdx.x;
    const int lane = tid & 63;
    const int wv = tid >> 6;
    const int c = lane & 15;
    const int g = lane >> 4;
    const int b = blockIdx.y;
    const int jbase = blockIdx.x * 64 + wv * 16;
    const short* Qbb = Qb + (size_t)b * TN * DN;

    bf16x8 a0 = *reinterpret_cast<const bf16x8*>(Qbb + (size_t)(jbase + c) * DN + g * 8);
    bf16x8 a1 = *reinterpret_cast<const bf16x8*>(Qbb + (size_t)(jbase + c) * DN + g * 8 + 32);

    const int srow = tid >> 2;      // 0..63 staged row
    const int schk = tid & 3;       // 0..3, 16 shorts each

    // prefetch ib=0
    bf16x8 v0 = *reinterpret_cast<const bf16x8*>(Qbb + (size_t)srow * DN + schk * 16);
    bf16x8 v1 = *reinterpret_cast<const bf16x8*>(Qbb + (size_t)srow * DN + schk * 16 + 8);

    float l[4] = {0.f, 0.f, 0.f, 0.f};
    for (int ib = 0; ib < TN; ib += 64) {
        __syncthreads();   // previous step's reads done before overwrite
        *reinterpret_cast<bf16x8*>(&Qt[srow * PAD + schk * 16]) = v0;
        *reinterpret_cast<bf16x8*>(&Qt[srow * PAD + schk * 16 + 8]) = v1;
        const int in_ = (ib + 64 < TN) ? ib + 64 : ib;
        v0 = *reinterpret_cast<const bf16x8*>(Qbb + (size_t)(in_ + srow) * DN + schk * 16);
        v1 = *reinterpret_cast<const bf16x8*>(Qbb + (size_t)(in_ + srow) * DN + schk * 16 + 8);
        __syncthreads();

        #pragma unroll
        for (int it = 0; it < 4; ++it) {
            bf16x8 b0 = *reinterpret_cast<const bf16x8*>(&Qt[(it * 16 + c) * PAD + g * 8]);
            bf16x8 b1 = *reinterpret_cast<const bf16x8*>(&Qt[(it * 16 + c) * PAD + g * 8 + 32]);
            f32x4 acc = {0.f, 0.f, 0.f, 0.f};
            acc = __builtin_amdgcn_mfma_f32_16x16x32_bf16(a0, b0, acc, 0, 0, 0);
            acc = __builtin_amdgcn_mfma_f32_16x16x32_bf16(a1, b1, acc, 0, 0, 0);
            #pragma unroll
            for (int r = 0; r < 4; ++r)
                l[r] += __expf(acc[r] * 0.125f);
        }
    }
    #pragma unroll
    for (int r = 0; r < 4; ++r) {
        float v = l[r];
        v += __shfl_xor(v, 1);
        v += __shfl_xor(v, 2);
        v += __shfl_xor(v, 4);
        v += __shfl_xor(v, 8);
        l[r] = v;
    }
    if (c == 0) {
        #pragma unroll
        for (int r = 0; r < 4; ++r)
            linv[(size_t)b * TN + jbase + g * 4 + r] = 1.0f / l[r];
    }
}

// ---------------------------------------------------------------------------
// Kernel C (v4): out[i,:] = sum_j exp(S[i,j]/8) * linv[j] * Q[j,:]
// Block = 64 i (4 waves x 16 i) -> grid 512 (2 blocks/CU). Register prefetch
// one j-tile ahead. Pt is wave-private: phase A->B ordered by lgkmcnt(0) +
// sched_barrier instead of a block barrier (2 barriers/iter total).
// ---------------------------------------------------------------------------
__global__ __launch_bounds__(256, 2) void pv_kernel(
    const short* __restrict__ Qb, const short* __restrict__ QTb,
    const float* __restrict__ linv, float* __restrict__ out)
{
    __shared__ short Qt[64 * PAD];        // Q[j-local][d]
    __shared__ short QTt[64 * PAD];       // QT[d][j-local]
    __shared__ short Pt[4][16 * PAD];     // per wave: P[i-local][j-local]
    __shared__ float lv[64];

    const int tid = threadIdx.x;
    const int lane = tid & 63;
    const int wv = tid >> 6;
    const int c = lane & 15;
    const int g = lane >> 4;
    const int b = blockIdx.y;
    const int ibase = blockIdx.x * 64 + wv * 16;
    const short* Qbb = Qb + (size_t)b * TN * DN;
    const short* QTbb = QTb + (size_t)b * DN * TN;
    const float* linvb = linv + (size_t)b * TN;

    bf16x8 bi0 = *reinterpret_cast<const bf16x8*>(Qbb + (size_t)(ibase + c) * DN + g * 8);
    bf16x8 bi1 = *reinterpret_cast<const bf16x8*>(Qbb + (size_t)(ibase + c) * DN + g * 8 + 32);

    f32x4 o[4];
    #pragma unroll
    for (int dt = 0; dt < 4; ++dt) o[dt] = (f32x4){0.f, 0.f, 0.f, 0.f};

    const int srow = tid >> 2;
    const int schk = tid & 3;

    // prefetch jb=0
    bf16x8 vq0 = *reinterpret_cast<const bf16x8*>(Qbb + (size_t)srow * DN + schk * 16);
    bf16x8 vq1 = *reinterpret_cast<const bf16x8*>(Qbb + (size_t)srow * DN + schk * 16 + 8);
    bf16x8 vt0 = *reinterpret_cast<const bf16x8*>(QTbb + (size_t)srow * TN + schk * 16);
    bf16x8 vt1 = *reinterpret_cast<const bf16x8*>(QTbb + (size_t)srow * TN + schk * 16 + 8);
    float vl = (tid < 64) ? linvb[tid] : 0.f;

    for (int jb = 0; jb < TN; jb += 64) {
        __syncthreads();   // all reads of Qt/QTt/lv from prev iter done
        *reinterpret_cast<bf16x8*>(&Qt[srow * PAD + schk * 16]) = vq0;
        *reinterpret_cast<bf16x8*>(&Qt[srow * PAD + schk * 16 + 8]) = vq1;
        *reinterpret_cast<bf16x8*>(&QTt[srow * PAD + schk * 16]) = vt0;
        *reinterpret_cast<bf16x8*>(&QTt[srow * PAD + schk * 16 + 8]) = vt1;
        if (tid < 64) lv[tid] = vl;

        // prefetch next j-tile (clamped reload on last iter)
        const int jn = (jb + 64 < TN) ? jb + 64 : jb;
        vq0 = *reinterpret_cast<const bf16x8*>(Qbb + (size_t)(jn + srow) * DN + schk * 16);
        vq1 = *reinterpret_cast<const bf16x8*>(Qbb + (size_t)(jn + srow) * DN + schk * 16 + 8);
        vt0 = *reinterpret_cast<const bf16x8*>(QTbb + (size_t)srow * TN + jn + schk * 16);
        vt1 = *reinterpret_cast<const bf16x8*>(QTbb + (size_t)srow * TN + jn + schk * 16 + 8);
        vl = (tid < 64) ? linvb[jn + tid] : 0.f;
        __syncthreads();

        // --- phase A: MFMA1 S^T tiles -> P -> Pt (wave-private, b64 writes) ---
        #pragma unroll
        for (int jt = 0; jt < 4; ++jt) {
            bf16x8 a0 = *reinterpret_cast<const bf16x8*>(&Qt[(jt * 16 + c) * PAD + g * 8]);
            bf16x8 a1 = *reinterpret_cast<const bf16x8*>(&Qt[(jt * 16 + c) * PAD + g * 8 + 32]);
            f32x4 accs = {0.f, 0.f, 0.f, 0.f};
            accs = __builtin_amdgcn_mfma_f32_16x16x32_bf16(a0, bi0, accs, 0, 0, 0);
            accs = __builtin_amdgcn_mfma_f32_16x16x32_bf16(a1, bi1, accs, 0, 0, 0);
            f32x4 lw = *reinterpret_cast<const f32x4*>(&lv[jt * 16 + g * 4]);
            bf16x4 pw;
            #pragma unroll
            for (int r = 0; r < 4; ++r)
                pw[r] = f2bf(__expf(accs[r] * 0.125f) * lw[r]);
            *reinterpret_cast<bf16x4*>(&Pt[wv][c * PAD + jt * 16 + g * 4]) = pw;
        }
        // same-wave LDS RAW ordering (Pt is wave-private; no block barrier)
        asm volatile("s_waitcnt lgkmcnt(0)" ::: "memory");
        __builtin_amdgcn_sched_barrier(0);

        // --- phase B: MFMA2 outT[d][i] += QT[d][j] * P[j][i] ---
        bf16x8 p0 = *reinterpret_cast<const bf16x8*>(&Pt[wv][c * PAD + g * 8]);
        bf16x8 p1 = *reinterpret_cast<const bf16x8*>(&Pt[wv][c * PAD + 32 + g * 8]);
        #pragma unroll
        for (int dt = 0; dt < 4; ++dt) {
            bf16x8 aq0 = *reinterpret_cast<const bf16x8*>(&QTt[(dt * 16 + c) * PAD + g * 8]);
            bf16x8 aq1 = *reinterpret_cast<const bf16x8*>(&QTt[(dt * 16 + c) * PAD + 32 + g * 8]);
            o[dt] = __builtin_amdgcn_mfma_f32_16x16x32_bf16(aq0, p0, o[dt], 0, 0, 0);
            o[dt] = __builtin_amdgcn_mfma_f32_16x16x32_bf16(aq1, p1, o[dt], 0, 0, 0);
        }
    }

    // epilogue: lane holds outT[dt*16+g*4+r][ibase+c] -> float4 stores
    float* outb = out + (size_t)b * TN * DN;
    #pragma unroll
    for (int dt = 0; dt < 4; ++dt) {
        float4 v4;
        v4.x = o[dt][0]; v4.y = o[dt][1]; v4.z = o[dt][2]; v4.w = o[dt][3];
        *reinterpret_cast<float4*>(&outb[(size_t)(ibase + c) * DN + dt * 16 + g * 4]) = v4;
    }
}

extern "C" void kernel_launch(void* const* d_in, const int* in_sizes, int n_in,
                              void* d_out, int out_size, void* d_ws, size_t ws_size,
                              hipStream_t stream) {
    const float* x  = (const float*)d_in[0];
    const float* Wq = (const float*)d_in[1];
    const float* bq = (const float*)d_in[2];
    float* out = (float*)d_out;

    short* Qb  = (short*)d_ws;                          // 4 MB
    short* QTb = Qb + (size_t)BN * TN * DN;             // 4 MB
    float* linv = (float*)(QTb + (size_t)BN * TN * DN); // 128 KB
    short* WTh = (short*)(linv + (size_t)BN * TN);      // 64 KB
    short* WTl = WTh + (size_t)DN * EN;                 // 64 KB

    wprep_kernel<<<dim3(EN / 64), dim3(256), 0, stream>>>(Wq, WTh, WTl);
    qproj_kernel<<<dim3(BN * TN / 64), dim3(256), 0, stream>>>(x, WTh, WTl, bq, Qb, QTb);
    stats_kernel<<<dim3(TN / 64, BN), dim3(256), 0, stream>>>(Qb, linv);
    pv_kernel<<<dim3(TN / 64, BN), dim3(256), 0, stream>>>(Qb, QTb, linv, out);
}